// Round 14
// baseline (455.811 us; speedup 1.0000x reference)
//
#include <hip/hip_runtime.h>
#include <hip/hip_cooperative_groups.h>
#include <math.h>

#define BATCH 16
#define LEN 480000
#define NDIM 9
#define CHUNK 1024
#define NCHUNK 469             /* ceil(480000/1024); last chunk = 768 elements */
#define TOTCH (NCHUNK * BATCH) /* 7504 chunk-tasks */
#define NBLK 1024              /* 4 blocks/CU * 256 CU -> co-resident for coop */
#define MAXJ 8                 /* ceil(7504/1024) chunks per block */
#define AMP 0.1f

namespace cg = cooperative_groups;

// native 4-float vector for nontemporal builtins (HIP float4 is a class type)
typedef float vfloat4 __attribute__((ext_vector_type(4)));

__device__ __forceinline__ float hw_fract(float x) {
#if __has_builtin(__builtin_amdgcn_fractf)
  return __builtin_amdgcn_fractf(x);
#else
  return x - floorf(x);
#endif
}
// sin(2*pi*x) for x in [0,1) — v_sin_f32 takes revolutions
__device__ __forceinline__ float hw_sin1(float x) {
#if __has_builtin(__builtin_amdgcn_sinf)
  return __builtin_amdgcn_sinf(x);
#else
  return __sinf(x * 6.283185307179586f);
#endif
}

// Raw barrier for write->barrier->read LDS handoff WITHOUT draining vmcnt
// (in-flight NT stores keep streaming). CRITICAL fix vs R5-R8:
// __builtin_amdgcn_s_barrier is IntrNoMem at IR level — NOT a compiler memory
// fence — so post-barrier LDS reads could hoist above it (this was the race:
// stale Al/Pl -> 0 written where ref=±0.1). Pin both sides:
//   pre:  s_waitcnt lgkmcnt(0) w/ memory clobber (own writes committed)
//   post: sched_barrier(0) + empty asm memory clobber (no read hoisting)
__device__ __forceinline__ void bar_lds() {
  asm volatile("s_waitcnt lgkmcnt(0)" ::: "memory");
  __builtin_amdgcn_s_barrier();
  __builtin_amdgcn_sched_barrier(0);
  asm volatile("" ::: "memory");
}

// ---------------- Fallback kernel A: per-1024-chunk f64 sums ----------------
__global__ __launch_bounds__(256) void sg_partial(const float* __restrict__ f0,
                                                  double* __restrict__ part) {
  const int c = blockIdx.x, b = blockIdx.y, t = threadIdx.x;
  const int i4 = c * 256 + t;
  float4 v = make_float4(0.f, 0.f, 0.f, 0.f);
  if (i4 < LEN / 4) v = ((const float4*)(f0 + (size_t)b * LEN))[i4];
  double s = (double)((v.x + v.y) + (v.z + v.w));
#pragma unroll
  for (int d = 32; d > 0; d >>= 1) s += __shfl_down(s, d, 64);
  __shared__ double ws[4];
  if ((t & 63) == 0) ws[t >> 6] = s;
  __syncthreads();
  if (t == 0) part[(size_t)b * NCHUNK + c] = (ws[0] + ws[1]) + (ws[2] + ws[3]);
}

// ---------------- Fallback kernel B: scan + sines (measured 322 µs) ---------
__global__ __launch_bounds__(256) void sg_main(const float* __restrict__ f0,
                                               const float* __restrict__ rand_ini,
                                               const double* __restrict__ part,
                                               float* __restrict__ out) {
  const int c = blockIdx.x, b = blockIdx.y, t = threadIdx.x;
  const int lane = t & 63, w = t >> 6;

  __shared__ __align__(16) float Pl[CHUNK + 4];
  __shared__ __align__(16) float Al[CHUNK + 4];
  __shared__ float2 Hl[NDIM];
  __shared__ float wsc[4];
  __shared__ double dred[4];

  const int i4 = c * 256 + t;
  float4 v = make_float4(0.f, 0.f, 0.f, 0.f);
  if (i4 < LEN / 4) v = ((const float4*)(f0 + (size_t)b * LEN))[i4];
  const float gs = (v.x + v.y) + (v.z + v.w);

  const double* prow = part + (size_t)b * NCHUNK;
  double s = 0.0;
  if (t < c) s += prow[t];
  if (t + 256 < c) s += prow[t + 256];
#pragma unroll
  for (int d = 32; d > 0; d >>= 1) s += __shfl_down(s, d, 64);
  if (lane == 0) dred[w] = s;

  float x = gs;
#pragma unroll
  for (int d = 1; d < 64; d <<= 1) {
    float y = __shfl_up(x, d, 64);
    if (lane >= d) x += y;
  }
  if (lane == 63) wsc[w] = x;
  __syncthreads();

  if (t < NDIM) {
    const double cb = (dred[0] + dred[1]) + (dred[2] + dred[3]);
    const double hs = (double)(t + 1) * (1.0 / 24000.0);
    double p0 = (double)rand_ini[b * NDIM + t] + hs * cb;
    p0 -= floor(p0);
    Hl[t] = make_float2((float)p0, (float)hs);
  }

  const float t0 = wsc[0], t1 = wsc[1], t2 = wsc[2];
  const float wpre = (w > 0 ? t0 : 0.f) + (w > 1 ? t1 : 0.f) + (w > 2 ? t2 : 0.f);
  const float Pex = wpre + (x - gs);

  const float p0v = Pex + v.x;
  const float p1v = p0v + v.y;
  const float p2v = p1v + v.z;
  const float p3v = p2v + v.w;
  {
    vfloat4 pq; pq.x = p0v; pq.y = p1v; pq.z = p2v; pq.w = p3v;
    *(vfloat4*)&Pl[4 * t] = pq;
    vfloat4 aq;
    aq.x = (v.x > 0.f) ? AMP : 0.f;
    aq.y = (v.y > 0.f) ? AMP : 0.f;
    aq.z = (v.z > 0.f) ? AMP : 0.f;
    aq.w = (v.w > 0.f) ? AMP : 0.f;
    *(vfloat4*)&Al[4 * t] = aq;
  }
  __syncthreads();

  vfloat4* out4 = (vfloat4*)out;
  const int base = c * CHUNK;
  const int valid = min(CHUNK, LEN - base);
  const int nf4 = (valid * NDIM) >> 2;
  const size_t gb4 = ((size_t)b * LEN * NDIM + (size_t)base * NDIM) >> 2;
  const int f0i = 4 * t;
  const int q0 = f0i / 9;
  const int r0 = f0i % 9;

#pragma unroll
  for (int k = 0; k < 9; ++k) {
    const int idx = k * 256 + t;
    const int K9 = (1024 * k) / 9;
    const int rk = (1024 * k) % 9;
    const int rsum = r0 + rk;
    const int carry = (rsum >= 9) ? 1 : 0;
    const int e = q0 + K9 + carry;
    const int r = rsum - 9 * carry;
    const float PA = Pl[e], PB = Pl[e + 1];
    const float aA = Al[e], aB = Al[e + 1];
    float res[4];
#pragma unroll
    for (int j = 0; j < 4; ++j) {
      const int h = r + j;
      const bool crs = (h >= 9);
      const int hh = crs ? h - 9 : h;
      const float2 ph = Hl[hh];
      const float Pe = crs ? PB : PA;
      const float am = crs ? aB : aA;
      res[j] = am * hw_sin1(hw_fract(ph.x + ph.y * Pe));
    }
    if (idx < nf4) {
      vfloat4 q; q.x = res[0]; q.y = res[1]; q.z = res[2]; q.w = res[3];
      __builtin_nontemporal_store(q, &out4[gb4 + idx]);
    }
  }

  const size_t uv4_base = ((size_t)BATCH * LEN * NDIM) / 4 + ((size_t)b * LEN) / 4;
  if (i4 < LEN / 4) {
    vfloat4 u;
    u.x = (v.x > 0.f) ? 1.f : 0.f;
    u.y = (v.y > 0.f) ? 1.f : 0.f;
    u.z = (v.z > 0.f) ? 1.f : 0.f;
    u.w = (v.w > 0.f) ? 1.f : 0.f;
    __builtin_nontemporal_store(u, &out4[uv4_base + i4]);
  }
}

// ---------------- Fused persistent cooperative kernel ----------------
__global__ __launch_bounds__(256, 4) void sg_fused(const float* __restrict__ f0,
                                                   const float* __restrict__ rand_ini,
                                                   double* __restrict__ part,
                                                   float* __restrict__ out) {
  const int k = blockIdx.x, t = threadIdx.x;
  const int lane = t & 63, w = t >> 6;

  __shared__ double ws1[4];
  __shared__ __align__(16) float Pl[2][CHUNK + 4];
  __shared__ __align__(16) float Al[2][CHUNK + 4];
  __shared__ float2 Hl[2][NDIM];
  __shared__ float wsc[2][4];
  __shared__ double dred[2][4];

  // ---------- phase 1: per-chunk f64 sums ----------
  for (int j = 0; j < MAXJ; ++j) {
    const int m = k + j * NBLK;       // block-uniform
    if (m >= TOTCH) break;
    const int b = m / NCHUNK, c = m - b * NCHUNK;
    const int i4 = c * 256 + t;
    float4 v = make_float4(0.f, 0.f, 0.f, 0.f);
    if (i4 < LEN / 4) v = ((const float4*)(f0 + (size_t)b * LEN))[i4];
    double s = (double)((v.x + v.y) + (v.z + v.w));
#pragma unroll
    for (int d = 32; d > 0; d >>= 1) s += __shfl_down(s, d, 64);
    if (lane == 0) ws1[w] = s;
    __syncthreads();
    if (t == 0) part[m] = (ws1[0] + ws1[1]) + (ws1[2] + ws1[3]);
    __syncthreads();                  // protect ws1 reuse next iteration
  }

  cg::this_grid().sync();

  // ---------- phase 2: scan + sines + stores ----------
  vfloat4* out4 = (vfloat4*)out;
  const size_t uvall = ((size_t)BATCH * LEN * NDIM) / 4;

  for (int j = 0; j < MAXJ; ++j) {
    const int m = k + j * NBLK;       // block-uniform
    if (m >= TOTCH) break;
    const int p = j & 1;
    const int b = m / NCHUNK, c = m - b * NCHUNK;
    const int i4 = c * 256 + t;

    float4 v = make_float4(0.f, 0.f, 0.f, 0.f);
    if (i4 < LEN / 4) v = ((const float4*)(f0 + (size_t)b * LEN))[i4];  // L2-hot
    const float gs = (v.x + v.y) + (v.z + v.w);

    const double* prow = part + (size_t)b * NCHUNK;
    double s = 0.0;
    if (t < c) s += prow[t];
    if (t + 256 < c) s += prow[t + 256];
#pragma unroll
    for (int d = 32; d > 0; d >>= 1) s += __shfl_down(s, d, 64);
    if (lane == 0) dred[p][w] = s;

    float x = gs;
#pragma unroll
    for (int d = 1; d < 64; d <<= 1) {
      float y = __shfl_up(x, d, 64);
      if (lane >= d) x += y;
    }
    if (lane == 63) wsc[p][w] = x;
    bar_lds();

    if (t < NDIM) {
      const double cb = (dred[p][0] + dred[p][1]) + (dred[p][2] + dred[p][3]);
      const double hs = (double)(t + 1) * (1.0 / 24000.0);
      double p0 = (double)rand_ini[b * NDIM + t] + hs * cb;
      p0 -= floor(p0);
      Hl[p][t] = make_float2((float)p0, (float)hs);
    }

    const float t0 = wsc[p][0], t1 = wsc[p][1], t2 = wsc[p][2];
    const float wpre = (w > 0 ? t0 : 0.f) + (w > 1 ? t1 : 0.f) + (w > 2 ? t2 : 0.f);
    const float Pex = wpre + (x - gs);

    const float p0v = Pex + v.x;
    const float p1v = p0v + v.y;
    const float p2v = p1v + v.z;
    const float p3v = p2v + v.w;
    {
      vfloat4 pq; pq.x = p0v; pq.y = p1v; pq.z = p2v; pq.w = p3v;
      *(vfloat4*)&Pl[p][4 * t] = pq;
      vfloat4 aq;
      aq.x = (v.x > 0.f) ? AMP : 0.f;
      aq.y = (v.y > 0.f) ? AMP : 0.f;
      aq.z = (v.z > 0.f) ? AMP : 0.f;
      aq.w = (v.w > 0.f) ? AMP : 0.f;
      *(vfloat4*)&Al[p][4 * t] = aq;
    }
    bar_lds();

    const int base = c * CHUNK;
    const int valid = min(CHUNK, LEN - base);
    const int nf4 = (valid * NDIM) >> 2;
    const size_t gb4 = ((size_t)b * LEN * NDIM + (size_t)base * NDIM) >> 2;
    const int f0i = 4 * t;
    const int q0 = f0i / 9;
    const int r0 = f0i % 9;

#pragma unroll
    for (int kk = 0; kk < 9; ++kk) {
      const int idx = kk * 256 + t;
      const int K9 = (1024 * kk) / 9;   // compile-time
      const int rk = (1024 * kk) % 9;   // compile-time
      const int rsum = r0 + rk;
      const int carry = (rsum >= 9) ? 1 : 0;
      const int e = q0 + K9 + carry;
      const int r = rsum - 9 * carry;
      const float PA = Pl[p][e], PB = Pl[p][e + 1];
      const float aA = Al[p][e], aB = Al[p][e + 1];
      float res[4];
#pragma unroll
      for (int jj = 0; jj < 4; ++jj) {
        const int h = r + jj;
        const bool crs = (h >= 9);
        const int hh = crs ? h - 9 : h;
        const float2 ph = Hl[p][hh];
        const float Pe = crs ? PB : PA;
        const float am = crs ? aB : aA;
        res[jj] = am * hw_sin1(hw_fract(ph.x + ph.y * Pe));
      }
      if (idx < nf4) {
        vfloat4 q; q.x = res[0]; q.y = res[1]; q.z = res[2]; q.w = res[3];
        __builtin_nontemporal_store(q, &out4[gb4 + idx]);
      }
    }

    if (i4 < LEN / 4) {
      vfloat4 u;
      u.x = (v.x > 0.f) ? 1.f : 0.f;
      u.y = (v.y > 0.f) ? 1.f : 0.f;
      u.z = (v.z > 0.f) ? 1.f : 0.f;
      u.w = (v.w > 0.f) ? 1.f : 0.f;
      __builtin_nontemporal_store(u, &out4[uvall + ((size_t)b * LEN) / 4 + i4]);
    }
  }
}

extern "C" void kernel_launch(void* const* d_in, const int* in_sizes, int n_in,
                              void* d_out, int out_size, void* d_ws, size_t ws_size,
                              hipStream_t stream) {
  const float* f0 = (const float*)d_in[0];
  const float* rand_ini = (const float*)d_in[1];
  float* out = (float*)d_out;
  double* part = (double*)d_ws;   // TOTCH f64 partial chunk sums (60 KB)

  void* args[] = {(void*)&f0, (void*)&rand_ini, (void*)&part, (void*)&out};
  hipError_t e = hipLaunchCooperativeKernel((const void*)sg_fused, dim3(NBLK),
                                            dim3(256), args, 0, stream);
  if (e != hipSuccess) {
    // cooperative launch unavailable -> proven two-kernel path (322 µs)
    dim3 grid(NCHUNK, BATCH);
    sg_partial<<<grid, 256, 0, stream>>>(f0, part);
    sg_main<<<grid, 256, 0, stream>>>(f0, rand_ini, part, out);
  }
}

// Round 15
// 324.009 us; speedup vs baseline: 1.4068x; 1.4068x over previous
//
#include <hip/hip_runtime.h>
#include <math.h>

#define BATCH 16
#define LEN 480000
#define NDIM 9
#define CHUNK 1024
#define NCHUNK 469   /* ceil(480000/1024); last chunk = 768 elements */
#define AMP 0.1f

// native 4-float vector for nontemporal builtins (HIP float4 is a class type)
typedef float vfloat4 __attribute__((ext_vector_type(4)));

__device__ __forceinline__ float hw_fract(float x) {
#if __has_builtin(__builtin_amdgcn_fractf)
  return __builtin_amdgcn_fractf(x);
#else
  return x - floorf(x);
#endif
}
// sin(2*pi*x) for x in [0,1) — v_sin_f32 takes revolutions
__device__ __forceinline__ float hw_sin1(float x) {
#if __has_builtin(__builtin_amdgcn_sinf)
  return __builtin_amdgcn_sinf(x);
#else
  return __sinf(x * 6.283185307179586f);
#endif
}

// ---------------- Kernel A: per-1024-chunk f64 sums of f0 ----------------
__global__ __launch_bounds__(256) void sg_partial(const float* __restrict__ f0,
                                                  double* __restrict__ part) {
  const int c = blockIdx.x, b = blockIdx.y, t = threadIdx.x;
  const int i4 = c * 256 + t;
  float4 v = make_float4(0.f, 0.f, 0.f, 0.f);
  if (i4 < LEN / 4) v = ((const float4*)(f0 + (size_t)b * LEN))[i4];
  double s = (double)((v.x + v.y) + (v.z + v.w));
#pragma unroll
  for (int d = 32; d > 0; d >>= 1) s += __shfl_down(s, d, 64);
  __shared__ double ws[4];
  if ((t & 63) == 0) ws[t >> 6] = s;
  __syncthreads();
  if (t == 0) part[(size_t)b * NCHUNK + c] = (ws[0] + ws[1]) + (ws[2] + ws[3]);
}

// ---------------- Kernel B: main — measured 322.285 µs ----------------
// LDS holds only the scan results (P[1024] + amp[1024], ~8.5 KB); sines are
// computed directly in coalesced store order (element/harmonic index via
// compile-time div-by-9), NT stores keep the 307 MB output stream from
// thrashing per-XCD L2. Measured equal to the 36 KB-tile variant (322.6) and
// faster than the fused cooperative variant (455.8) -> this structure is at
// the streaming-write roofline; remaining headline time is fixed harness cost.
__global__ __launch_bounds__(256) void sg_main(const float* __restrict__ f0,
                                               const float* __restrict__ rand_ini,
                                               const double* __restrict__ part,
                                               float* __restrict__ out) {
  const int c = blockIdx.x, b = blockIdx.y, t = threadIdx.x;
  const int lane = t & 63, w = t >> 6;

  __shared__ __align__(16) float Pl[CHUNK + 4];  // inclusive prefix per element
  __shared__ __align__(16) float Al[CHUNK + 4];  // amp (0.1*uv) per element
  __shared__ float2 Hl[NDIM];                    // {phi0, hsf} per harmonic
  __shared__ float wsc[4];
  __shared__ double dred[4];

  // --- load this thread's 4 elements (coalesced float4) ---
  const int i4 = c * 256 + t;
  float4 v = make_float4(0.f, 0.f, 0.f, 0.f);
  if (i4 < LEN / 4) v = ((const float4*)(f0 + (size_t)b * LEN))[i4];
  const float gs = (v.x + v.y) + (v.z + v.w);

  // --- block-parallel f64 sum of preceding chunk sums ---
  const double* prow = part + (size_t)b * NCHUNK;
  double s = 0.0;
  if (t < c) s += prow[t];
  if (t + 256 < c) s += prow[t + 256];
#pragma unroll
  for (int d = 32; d > 0; d >>= 1) s += __shfl_down(s, d, 64);
  if (lane == 0) dred[w] = s;

  // --- wave-level inclusive scan of per-thread group sums ---
  float x = gs;
#pragma unroll
  for (int d = 1; d < 64; d <<= 1) {
    float y = __shfl_up(x, d, 64);
    if (lane >= d) x += y;
  }
  if (lane == 63) wsc[w] = x;
  __syncthreads();

  // --- per-harmonic base phase, computed by 9 threads only ---
  if (t < NDIM) {
    const double cb = (dred[0] + dred[1]) + (dred[2] + dred[3]);
    const double hs = (double)(t + 1) * (1.0 / 24000.0);
    double p0 = (double)rand_ini[b * NDIM + t] + hs * cb;
    p0 -= floor(p0);
    Hl[t] = make_float2((float)p0, (float)hs);
  }

  const float t0 = wsc[0], t1 = wsc[1], t2 = wsc[2];
  const float wpre = (w > 0 ? t0 : 0.f) + (w > 1 ? t1 : 0.f) + (w > 2 ? t2 : 0.f);
  const float Pex = wpre + (x - gs);    // exclusive in-chunk prefix

  // --- per-element inclusive prefix + amp into LDS (b128, 2-way = free) ---
  const float p0v = Pex + v.x;
  const float p1v = p0v + v.y;
  const float p2v = p1v + v.z;
  const float p3v = p2v + v.w;
  {
    vfloat4 pq; pq.x = p0v; pq.y = p1v; pq.z = p2v; pq.w = p3v;
    *(vfloat4*)&Pl[4 * t] = pq;
    vfloat4 aq;
    aq.x = (v.x > 0.f) ? AMP : 0.f;
    aq.y = (v.y > 0.f) ? AMP : 0.f;
    aq.z = (v.z > 0.f) ? AMP : 0.f;
    aq.w = (v.w > 0.f) ? AMP : 0.f;
    *(vfloat4*)&Al[4 * t] = aq;
  }
  __syncthreads();

  // --- compute sines directly in coalesced store order ---
  vfloat4* out4 = (vfloat4*)out;
  const int base = c * CHUNK;
  const int valid = min(CHUNK, LEN - base);
  const int nf4 = (valid * NDIM) >> 2;
  const size_t gb4 = ((size_t)b * LEN * NDIM + (size_t)base * NDIM) >> 2;

  const int f0i = 4 * t;            // first float index owned this iteration
  const int q0 = f0i / 9;           // magic-div by compiler
  const int r0 = f0i % 9;

#pragma unroll
  for (int k = 0; k < 9; ++k) {
    const int idx = k * 256 + t;    // float4 index within chunk
    const int K9 = (1024 * k) / 9;  // compile-time
    const int rk = (1024 * k) % 9;  // compile-time
    const int rsum = r0 + rk;       // [0,16]
    const int carry = (rsum >= 9) ? 1 : 0;
    const int e = q0 + K9 + carry;  // element of float 4*idx
    const int r = rsum - 9 * carry; // harmonic of float 4*idx
    const float PA = Pl[e], PB = Pl[e + 1];
    const float aA = Al[e], aB = Al[e + 1];
    float res[4];
#pragma unroll
    for (int j = 0; j < 4; ++j) {
      const int h = r + j;
      const bool crs = (h >= 9);
      const int hh = crs ? h - 9 : h;
      const float2 ph = Hl[hh];                 // LDS lookup, mostly broadcast
      const float Pe = crs ? PB : PA;
      const float am = crs ? aB : aA;
      res[j] = am * hw_sin1(hw_fract(ph.x + ph.y * Pe));
    }
    if (idx < nf4) {
      vfloat4 q; q.x = res[0]; q.y = res[1]; q.z = res[2]; q.w = res[3];
      __builtin_nontemporal_store(q, &out4[gb4 + idx]);
    }
  }

  // --- uv store (from registers, coalesced) ---
  const size_t uv4_base = ((size_t)BATCH * LEN * NDIM) / 4 + ((size_t)b * LEN) / 4;
  if (i4 < LEN / 4) {
    vfloat4 u;
    u.x = (v.x > 0.f) ? 1.f : 0.f;
    u.y = (v.y > 0.f) ? 1.f : 0.f;
    u.z = (v.z > 0.f) ? 1.f : 0.f;
    u.w = (v.w > 0.f) ? 1.f : 0.f;
    __builtin_nontemporal_store(u, &out4[uv4_base + i4]);
  }
}

extern "C" void kernel_launch(void* const* d_in, const int* in_sizes, int n_in,
                              void* d_out, int out_size, void* d_ws, size_t ws_size,
                              hipStream_t stream) {
  const float* f0 = (const float*)d_in[0];
  const float* rand_ini = (const float*)d_in[1];
  float* out = (float*)d_out;

  double* part = (double*)d_ws;   // BATCH*NCHUNK f64 partial chunk sums

  dim3 grid(NCHUNK, BATCH);
  sg_partial<<<grid, 256, 0, stream>>>(f0, part);
  sg_main<<<grid, 256, 0, stream>>>(f0, rand_ini, part, out);
}